// Round 5
// baseline (42.398 us; speedup 1.0000x reference)
//
#include <hip/hip_runtime.h>

// GetScalars: per (b,n) atom, complex Gram matrices over the m-dim for
// l=0..3 plus interleaved l=0 passthrough. Output complex64.
//
// Output sizing is derived from out_size at launch (defensive — round 1
// core-dumped, prime suspect was assuming out_size counts floats):
//   fpa = out_size / atoms == 2112 -> interleaved (re,im) float pairs
//   fpa == 1056                    -> real parts only (.real-cast ref)

#define GS_STAGE_LDS()                                                        \
    __shared__ float s[512];                                                  \
    {                                                                         \
        const size_t a = (size_t)blockIdx.x;                                  \
        for (int f = threadIdx.x; f < 512; f += 256) {                        \
            const float* src; int off;                                        \
            if (f < 16)       { src = p0re + a * 16;  off = f; }              \
            else if (f < 32)  { src = p0im + a * 16;  off = f - 16; }         \
            else if (f < 80)  { src = p1re + a * 48;  off = f - 32; }         \
            else if (f < 128) { src = p1im + a * 48;  off = f - 80; }         \
            else if (f < 208) { src = p2re + a * 80;  off = f - 128; }        \
            else if (f < 288) { src = p2im + a * 80;  off = f - 208; }        \
            else if (f < 400) { src = p3re + a * 112; off = f - 288; }        \
            else              { src = p3im + a * 112; off = f - 400; }        \
            s[f] = src[off];                                                  \
        }                                                                     \
    }                                                                         \
    __syncthreads();

__global__ __launch_bounds__(256) void getscalars_pairs(
    const float* __restrict__ p0re, const float* __restrict__ p0im,
    const float* __restrict__ p1re, const float* __restrict__ p1im,
    const float* __restrict__ p2re, const float* __restrict__ p2im,
    const float* __restrict__ p3re, const float* __restrict__ p3im,
    float* __restrict__ out)
{
    const int t = threadIdx.x;
    GS_STAGE_LDS();

    float2* cbase = (float2*)(out + (size_t)blockIdx.x * 2112);

    if (t < 32) {
        float vr = (t & 1) ? s[16 + (t >> 1)] : s[t >> 1];
        cbase[t] = make_float2(vr, 0.0f);
    }

    const int c1 = t >> 4, c2 = t & 15;
    const int roff[4] = { 0, 32, 128, 288 };
    const int ioff[4] = { 16, 80, 208, 400 };
    const int Ms[4]   = { 1, 3, 5, 7 };

    #pragma unroll
    for (int l = 0; l < 4; ++l) {
        const float* re = s + roff[l];
        const float* im = s + ioff[l];
        float gr = 0.0f, gi = 0.0f;
        #pragma unroll
        for (int m = 0; m < Ms[l]; ++m) {
            float r1 = re[m * 16 + c1], r2 = re[m * 16 + c2];
            float i1 = im[m * 16 + c1], i2 = im[m * 16 + c2];
            gr += r1 * r2 + i1 * i2;
            gi += i1 * r2 - r1 * i2;
        }
        cbase[32 + l * 256 + t] = make_float2(gr, gi);
    }
}

__global__ __launch_bounds__(256) void getscalars_real(
    const float* __restrict__ p0re, const float* __restrict__ p0im,
    const float* __restrict__ p1re, const float* __restrict__ p1im,
    const float* __restrict__ p2re, const float* __restrict__ p2im,
    const float* __restrict__ p3re, const float* __restrict__ p3im,
    float* __restrict__ out)
{
    const int t = threadIdx.x;
    GS_STAGE_LDS();

    float* base = out + (size_t)blockIdx.x * 1056;

    if (t < 32) {
        base[t] = (t & 1) ? s[16 + (t >> 1)] : s[t >> 1];
    }

    const int c1 = t >> 4, c2 = t & 15;
    const int roff[4] = { 0, 32, 128, 288 };
    const int ioff[4] = { 16, 80, 208, 400 };
    const int Ms[4]   = { 1, 3, 5, 7 };

    #pragma unroll
    for (int l = 0; l < 4; ++l) {
        const float* re = s + roff[l];
        const float* im = s + ioff[l];
        float gr = 0.0f;
        #pragma unroll
        for (int m = 0; m < Ms[l]; ++m) {
            gr += re[m * 16 + c1] * re[m * 16 + c2]
                + im[m * 16 + c1] * im[m * 16 + c2];
        }
        base[32 + l * 256 + t] = gr;
    }
}

extern "C" void kernel_launch(void* const* d_in, const int* in_sizes, int n_in,
                              void* d_out, int out_size, void* d_ws, size_t ws_size,
                              hipStream_t stream) {
    const float* p0re = (const float*)d_in[0];
    const float* p0im = (const float*)d_in[1];
    const float* p1re = (const float*)d_in[2];
    const float* p1im = (const float*)d_in[3];
    const float* p2re = (const float*)d_in[4];
    const float* p2im = (const float*)d_in[5];
    const float* p3re = (const float*)d_in[6];
    const float* p3im = (const float*)d_in[7];
    float* out = (float*)d_out;

    const int atoms = in_sizes[0] / 16;          // B*N
    const long long fpa = (long long)out_size / atoms;

    if (fpa >= 2112) {
        getscalars_pairs<<<atoms, 256, 0, stream>>>(
            p0re, p0im, p1re, p1im, p2re, p2im, p3re, p3im, out);
    } else {
        getscalars_real<<<atoms, 256, 0, stream>>>(
            p0re, p0im, p1re, p1im, p2re, p2im, p3re, p3im, out);
    }
}

// Round 6
// 38.160 us; speedup vs baseline: 1.1111x; 1.1111x over previous
//
#include <hip/hip_runtime.h>

// GetScalars: per (b,n) atom, REAL part of complex Gram matrices over the
// m-dim for l=0..3 plus interleaved l=0 passthrough.
//
// Ground truth established R5: out_size counts complex64 elements
// (32768*1056), the buffer holds out_size float32, and validation compares
// real parts only. Any kernel writing 2112 floats/atom faults (R0/R3/R4).
//
// v2: wave w handles l=w (64 lanes x float4 = 256 entries of g_re);
// float4 LDS staging, float4 stores (1KB/wave/instr).

__global__ __launch_bounds__(256) void getscalars_real_v2(
    const float* __restrict__ p0re, const float* __restrict__ p0im,
    const float* __restrict__ p1re, const float* __restrict__ p1im,
    const float* __restrict__ p2re, const float* __restrict__ p2im,
    const float* __restrict__ p3re, const float* __restrict__ p3im,
    float* __restrict__ out)
{
    const int t = threadIdx.x;
    const size_t a = (size_t)blockIdx.x;

    // LDS float layout: [0,16) p0re | [16,32) p0im | [32,80) p1re |
    // [80,128) p1im | [128,208) p2re | [208,288) p2im | [288,400) p3re |
    // [400,512) p3im
    __shared__ float s[512];
    float4* s4 = (float4*)s;

    if (t < 128) {                      // 128 float4 = 512 floats
        const float4* src; int off;
        if (t < 8)       { src = (const float4*)((t < 4   ? p0re : p0im) + a * 16);  off = t & 3; }
        else if (t < 32) { src = (const float4*)((t < 20  ? p1re : p1im) + a * 48);  off = (t < 20)  ? t - 8  : t - 20; }
        else if (t < 72) { src = (const float4*)((t < 52  ? p2re : p2im) + a * 80);  off = (t < 52)  ? t - 32 : t - 52; }
        else             { src = (const float4*)((t < 100 ? p3re : p3im) + a * 112); off = (t < 100) ? t - 72 : t - 100; }
        s4[t] = src[off];
    }
    __syncthreads();

    float4* obase = (float4*)(out + a * 1056);   // 264 float4 per atom

    // part0 (32 floats = 8 quads): (re0[2j], im0[2j], re0[2j+1], im0[2j+1])
    if (t < 8) {
        obase[t] = make_float4(s[2 * t], s[16 + 2 * t],
                               s[2 * t + 1], s[16 + 2 * t + 1]);
    }

    // Gram real part: wave w = l; lane e covers row c1 = e>>2,
    // cols [4*(e&3), 4*(e&3)+4).
    const int e  = t & 63;
    const int c1 = e >> 2;
    const int q2 = e & 3;
    const int w  = t >> 6;

    float4 acc = make_float4(0.0f, 0.0f, 0.0f, 0.0f);

#define GS_GRAM_Q(RO, IO, M)                                                  \
    {                                                                         \
        _Pragma("unroll")                                                     \
        for (int m = 0; m < (M); ++m) {                                       \
            const float  r1 = s[(RO) + m * 16 + c1];                          \
            const float  i1 = s[(IO) + m * 16 + c1];                          \
            const float4 r2 = s4[((RO) >> 2) + m * 4 + q2];                   \
            const float4 i2 = s4[((IO) >> 2) + m * 4 + q2];                   \
            acc.x += r1 * r2.x + i1 * i2.x;                                   \
            acc.y += r1 * r2.y + i1 * i2.y;                                   \
            acc.z += r1 * r2.z + i1 * i2.z;                                   \
            acc.w += r1 * r2.w + i1 * i2.w;                                   \
        }                                                                     \
    }

    if      (w == 0) GS_GRAM_Q(0,   16,  1)
    else if (w == 1) GS_GRAM_Q(32,  80,  3)
    else if (w == 2) GS_GRAM_Q(128, 208, 5)
    else             GS_GRAM_Q(288, 400, 7)
#undef GS_GRAM_Q

    obase[8 + w * 64 + e] = acc;    // max quad index 263 -> 1056 floats/atom
}

// ---- Defensive fallback (R2-proven, only taken if out really holds pairs) --

#define GS_STAGE_LDS()                                                        \
    __shared__ float s[512];                                                  \
    {                                                                         \
        const size_t a = (size_t)blockIdx.x;                                  \
        for (int f = threadIdx.x; f < 512; f += 256) {                        \
            const float* src; int off;                                        \
            if (f < 16)       { src = p0re + a * 16;  off = f; }              \
            else if (f < 32)  { src = p0im + a * 16;  off = f - 16; }         \
            else if (f < 80)  { src = p1re + a * 48;  off = f - 32; }         \
            else if (f < 128) { src = p1im + a * 48;  off = f - 80; }         \
            else if (f < 208) { src = p2re + a * 80;  off = f - 128; }        \
            else if (f < 288) { src = p2im + a * 80;  off = f - 208; }        \
            else if (f < 400) { src = p3re + a * 112; off = f - 288; }        \
            else              { src = p3im + a * 112; off = f - 400; }        \
            s[f] = src[off];                                                  \
        }                                                                     \
    }                                                                         \
    __syncthreads();

__global__ __launch_bounds__(256) void getscalars_pairs(
    const float* __restrict__ p0re, const float* __restrict__ p0im,
    const float* __restrict__ p1re, const float* __restrict__ p1im,
    const float* __restrict__ p2re, const float* __restrict__ p2im,
    const float* __restrict__ p3re, const float* __restrict__ p3im,
    float* __restrict__ out)
{
    const int t = threadIdx.x;
    GS_STAGE_LDS();

    float2* cbase = (float2*)(out + (size_t)blockIdx.x * 2112);

    if (t < 32) {
        float vr = (t & 1) ? s[16 + (t >> 1)] : s[t >> 1];
        cbase[t] = make_float2(vr, 0.0f);
    }

    const int c1 = t >> 4, c2 = t & 15;
    const int roff[4] = { 0, 32, 128, 288 };
    const int ioff[4] = { 16, 80, 208, 400 };
    const int Ms[4]   = { 1, 3, 5, 7 };

    #pragma unroll
    for (int l = 0; l < 4; ++l) {
        const float* re = s + roff[l];
        const float* im = s + ioff[l];
        float gr = 0.0f, gi = 0.0f;
        #pragma unroll
        for (int m = 0; m < Ms[l]; ++m) {
            float r1 = re[m * 16 + c1], r2 = re[m * 16 + c2];
            float i1 = im[m * 16 + c1], i2 = im[m * 16 + c2];
            gr += r1 * r2 + i1 * i2;
            gi += i1 * r2 - r1 * i2;
        }
        cbase[32 + l * 256 + t] = make_float2(gr, gi);
    }
}

extern "C" void kernel_launch(void* const* d_in, const int* in_sizes, int n_in,
                              void* d_out, int out_size, void* d_ws, size_t ws_size,
                              hipStream_t stream) {
    const float* p0re = (const float*)d_in[0];
    const float* p0im = (const float*)d_in[1];
    const float* p1re = (const float*)d_in[2];
    const float* p1im = (const float*)d_in[3];
    const float* p2re = (const float*)d_in[4];
    const float* p2im = (const float*)d_in[5];
    const float* p3re = (const float*)d_in[6];
    const float* p3im = (const float*)d_in[7];
    float* out = (float*)d_out;

    const int atoms = in_sizes[0] / 16;          // B*N
    const long long fpa = (long long)out_size / atoms;

    if (fpa >= 2112) {
        getscalars_pairs<<<atoms, 256, 0, stream>>>(
            p0re, p0im, p1re, p1im, p2re, p2im, p3re, p3im, out);
    } else {
        getscalars_real_v2<<<atoms, 256, 0, stream>>>(
            p0re, p0im, p1re, p1im, p2re, p2im, p3re, p3im, out);
    }
}